// Round 6
// baseline (294.846 us; speedup 1.0000x reference)
//
#include <hip/hip_runtime.h>
#include <hip/hip_bf16.h>

// SelfAttentionLayer: B=64 S=512 E=512 H=8 D=64
// Round 12: consolidation + attn pipelining.
//  - qkv_gemm: reverted to round-4 staging/gates (best measured 77.6us;
//    round-5 gate restructure was null/-2%).
//  - outproj: reverted to __syncthreads 2-phase dbuf (counted-2ph pattern
//    cost ~10us on qkv in round 3; same structure -> revert).
//  - attn_kernel: K/V double-buffered with counted vmcnt(4) gates; mask row
//    preloaded in prologue (uniform per-wave vmcnt). Per-chunk compute
//    (~1100cy: 64 MFMA + 64 exp2 + pack) >> load latency -> T4 applies here
//    unlike qkv's 2-phase. 8 full vmcnt(0) drains removed per block.

#define Bn 64
#define Sn 512
#define En 512
#define Hn 8
#define Dn 64

typedef __attribute__((ext_vector_type(8))) short s8v;   // 8 bf16 = 4 VGPRs
typedef __attribute__((ext_vector_type(4))) float f4v;   // 4 fp32 acc

__device__ __forceinline__ unsigned short f2bf(float f) {
    union { float f; unsigned int u; } v; v.f = f;
    unsigned int u = v.u;
    u += 0x7fffu + ((u >> 16) & 1u);   // round-to-nearest-even
    return (unsigned short)(u >> 16);
}

__device__ __forceinline__ void async16(const unsigned short* g, unsigned short* l) {
    __builtin_amdgcn_global_load_lds((const __attribute__((address_space(1))) void*)g,
                                     (__attribute__((address_space(3))) void*)l, 16, 0, 0);
}
__device__ __forceinline__ void async4(const float* g, float* l) {
    __builtin_amdgcn_global_load_lds((const __attribute__((address_space(1))) void*)g,
                                     (__attribute__((address_space(3))) void*)l, 4, 0, 0);
}

// ---------------------------------------------------------------- prep_h
__global__ __launch_bounds__(256) void prep_h(const float* __restrict__ x,
                                              const float* __restrict__ BE,
                                              unsigned short* __restrict__ hbf) {
    int i = (blockIdx.x * 256 + threadIdx.x) * 4;
    int se = i % (Sn * En);
    float4 a = *(const float4*)(x + i);
    float4 b = *(const float4*)(BE + se);
    ushort4 o;
    o.x = f2bf(a.x + b.x); o.y = f2bf(a.y + b.y);
    o.z = f2bf(a.z + b.z); o.w = f2bf(a.w + b.w);
    *(ushort4*)(hbf + i) = o;
}

// ---------------------------------------------------------------- prep_w
__global__ __launch_bounds__(256) void prep_w(const float* __restrict__ WQ,
                                              const float* __restrict__ WK,
                                              const float* __restrict__ WV,
                                              const float* __restrict__ WO,
                                              unsigned short* __restrict__ Wqkvt,
                                              unsigned short* __restrict__ WOt) {
    int idx = blockIdx.x * 256 + threadIdx.x;
    const int NW = 3 * Hn * Dn * En;                   // 786432
    if (idx < NW) {
        int e = idx & 511;
        int d = (idx >> 9) & 63;
        int h = (idx >> 15) & 7;
        int m = idx >> 18;
        const float* W = (m == 0) ? WQ : (m == 1) ? WK : WV;
        Wqkvt[idx] = f2bf(W[(h * En + e) * Dn + d]);   // [m][h][d][e]
    } else {
        int j = idx - NW;
        int n = j & 511;
        int e = j >> 9;
        WOt[j] = f2bf(WO[n * En + e]);                  // WO_t[e][hd]
    }
}

// ---------------------------------------------------------------- qkv_gemm
// C[32768,1536] = hbf[32768,512] x Wqkvt^T. 8-phase 256^2 schedule
// (round-4 staging/gates — best measured).
__device__ __forceinline__ void mfma8(const s8v& a0k0, const s8v& a0k1,
                                      const s8v& a1k0, const s8v& a1k1,
                                      f4v* acc0, f4v* acc1,
                                      const s8v (&bq)[4][2], bool sw) {
    if (sw) {
#pragma unroll
        for (int n = 0; n < 4; n++) {
            acc0[n] = __builtin_amdgcn_mfma_f32_16x16x32_bf16(bq[n][0], a0k0, acc0[n], 0, 0, 0);
            acc0[n] = __builtin_amdgcn_mfma_f32_16x16x32_bf16(bq[n][1], a0k1, acc0[n], 0, 0, 0);
            acc1[n] = __builtin_amdgcn_mfma_f32_16x16x32_bf16(bq[n][0], a1k0, acc1[n], 0, 0, 0);
            acc1[n] = __builtin_amdgcn_mfma_f32_16x16x32_bf16(bq[n][1], a1k1, acc1[n], 0, 0, 0);
        }
    } else {
#pragma unroll
        for (int n = 0; n < 4; n++) {
            acc0[n] = __builtin_amdgcn_mfma_f32_16x16x32_bf16(a0k0, bq[n][0], acc0[n], 0, 0, 0);
            acc0[n] = __builtin_amdgcn_mfma_f32_16x16x32_bf16(a0k1, bq[n][1], acc0[n], 0, 0, 0);
            acc1[n] = __builtin_amdgcn_mfma_f32_16x16x32_bf16(a1k0, bq[n][0], acc1[n], 0, 0, 0);
            acc1[n] = __builtin_amdgcn_mfma_f32_16x16x32_bf16(a1k1, bq[n][1], acc1[n], 0, 0, 0);
        }
    }
}

__global__ __launch_bounds__(512, 2) void qkv_gemm(const unsigned short* __restrict__ hbf,
                                                   const unsigned short* __restrict__ Wqkvt,
                                                   unsigned short* __restrict__ Qo,
                                                   unsigned short* __restrict__ Ko,
                                                   unsigned short* __restrict__ Vt) {
    __shared__ __align__(16) unsigned short As[2][16384];   // 64KB
    __shared__ __align__(16) unsigned short Bs[2][16384];   // 64KB

    int lin = blockIdx.y * 6 + blockIdx.x;                  // 768 blocks
    int swz = (lin & 7) * 96 + (lin >> 3);                  // bijective XCD swizzle
    int mb = swz / 6, nbv = swz - mb * 6;

    int tid = threadIdx.x;
    int w = tid >> 6, lane = tid & 63, quad = lane >> 4, l16 = lane & 15, l7 = l16 & 7;
    int wr = w >> 2, wcn = w & 3;

    const unsigned short* Ag = hbf + (size_t)mb * 256 * 512;
    const unsigned short* Bg = Wqkvt + (size_t)nbv * 256 * 512;

    int colbase = nbv * 256 + wcn * 64;
    bool swapQK = colbase < 1024;

    // staging address constants (pre-swizzled global source, linear LDS dst)
    int ha = (lane >> 3) & 1;                               // A hi/lo half
    int ca = w * 4 + (lane >> 4);                           // A m-part 0..31
    int aG0 = (ca + 128 * ha) * 512 + ((lane & 7) ^ (ca & 7)) * 8;
    int rb0 = w * 8 + (lane >> 3);                          // B row 0..63
    int bG0 = rb0 * 512 + ((lane & 7) ^ (rb0 & 7)) * 8;

    // ds_read constants
    int arow = 2 * l16 + wr;                                // A interleaved row term
    int aseg0 = (quad ^ l7) * 8;                            // ks=0 swizzled seg
    int aseg1 = ((4 + quad) ^ l7) * 8;                      // ks=1

    f4v acc[8][4];
#pragma unroll
    for (int i = 0; i < 8; i++)
#pragma unroll
        for (int n = 0; n < 4; n++) acc[i][n] = (f4v){0.f, 0.f, 0.f, 0.f};
    s8v bq[4][2];

#define STA8(o_, p_, kt_) async16(Ag + aG0 + (p_) * 16384 + (kt_) * 64, &As[o_][(p_) * 4096 + w * 512])
#define STB8(o_, q_, kt_) async16(Bg + bG0 + (q_) * 32768 + (kt_) * 64, &Bs[o_][(q_) * 4096 + w * 512])

#define PHASE8(P, STAGES, GATE)                                                   \
    do {                                                                          \
        if ((P) == 0) {                                                           \
            _Pragma("unroll")                                                     \
            for (int n = 0; n < 4; n++) {                                         \
                int br = (wcn * 64 + n * 16 + l16) * 64;                          \
                bq[n][0] = *(const s8v*)&Bs_s[br + aseg0];                        \
                bq[n][1] = *(const s8v*)&Bs_s[br + aseg1];                        \
            }                                                                     \
        }                                                                         \
        s8v a0k0 = *(const s8v*)&As_s[(((P) * 2 + 0) * 32 + arow) * 64 + aseg0];  \
        s8v a0k1 = *(const s8v*)&As_s[(((P) * 2 + 0) * 32 + arow) * 64 + aseg1];  \
        s8v a1k0 = *(const s8v*)&As_s[(((P) * 2 + 1) * 32 + arow) * 64 + aseg0];  \
        s8v a1k1 = *(const s8v*)&As_s[(((P) * 2 + 1) * 32 + arow) * 64 + aseg1];  \
        STAGES;                                                                   \
        __builtin_amdgcn_s_barrier();                                             \
        asm volatile("s_waitcnt lgkmcnt(0)" ::: "memory");                        \
        __builtin_amdgcn_s_setprio(1);                                            \
        mfma8(a0k0, a0k1, a1k0, a1k1, &acc[(P) * 2][0], &acc[(P) * 2 + 1][0], bq, swapQK); \
        __builtin_amdgcn_s_setprio(0);                                            \
        GATE;                                                                     \
        __builtin_amdgcn_s_barrier();                                             \
    } while (0)

    // prologue: K-tile 0 fully staged into slot 0, drained once
    STB8(0, 0, 0); STB8(0, 1, 0); STB8(0, 2, 0); STB8(0, 3, 0);
    STA8(0, 0, 0); STA8(0, 1, 0); STA8(0, 2, 0); STA8(0, 3, 0);
    asm volatile("s_waitcnt vmcnt(0)" ::: "memory");
    __builtin_amdgcn_s_barrier();

    for (int k = 0; k < 7; k++) {
        int s = k & 1, o = s ^ 1, kt = k + 1;
        const unsigned short* As_s = &As[s][0];
        const unsigned short* Bs_s = &Bs[s][0];
        PHASE8(0, { STB8(o, 0, kt); STB8(o, 1, kt); STA8(o, 0, kt); },
               asm volatile("s_waitcnt vmcnt(6)" ::: "memory"));
        PHASE8(1, { STB8(o, 2, kt); STA8(o, 1, kt); },
               asm volatile("s_waitcnt vmcnt(6)" ::: "memory"));
        PHASE8(2, { STB8(o, 3, kt); STA8(o, 2, kt); },
               asm volatile("s_waitcnt vmcnt(7)" ::: "memory"));
        PHASE8(3, { STA8(o, 3, kt); },
               asm volatile("s_waitcnt vmcnt(2)" ::: "memory"));
    }
    {   // tail K-tile 7 (slot 1): no staging, gradual drain
        const unsigned short* As_s = &As[1][0];
        const unsigned short* Bs_s = &Bs[1][0];
        PHASE8(0, {}, asm volatile("s_waitcnt vmcnt(3)" ::: "memory"));
        PHASE8(1, {}, asm volatile("s_waitcnt vmcnt(1)" ::: "memory"));
        PHASE8(2, {}, asm volatile("s_waitcnt vmcnt(0)" ::: "memory"));
        PHASE8(3, {}, (void)0);
    }
#undef PHASE8
#undef STA8
#undef STB8

    int mat = colbase >> 9;
    int h = (colbase >> 6) & 7;
    int b_idx = mb >> 1;
    const float qscale = 0.06375873f;   // log2(e)/sqrt(512): scale + exp->exp2 fold

    if (swapQK) {
        unsigned short* op = (mat == 0) ? Qo : Ko;
        float sc = (mat == 0) ? qscale : 1.0f;
#pragma unroll
        for (int mi = 0; mi < 8; mi++)
#pragma unroll
            for (int n = 0; n < 4; n++) {
                int s_ = (mb & 1) * 256 + wr * 128 + mi * 16 + l16;
                int d0 = n * 16 + quad * 4;
                ushort4 pk;
                pk.x = f2bf(acc[mi][n][0] * sc);
                pk.y = f2bf(acc[mi][n][1] * sc);
                pk.z = f2bf(acc[mi][n][2] * sc);
                pk.w = f2bf(acc[mi][n][3] * sc);
                *(ushort4*)&op[(size_t)((b_idx * Hn + h) * Sn + s_) * Dn + d0] = pk;
            }
    } else {
#pragma unroll
        for (int mi = 0; mi < 8; mi++)
#pragma unroll
            for (int n = 0; n < 4; n++) {
                int d = n * 16 + l16;
                int srow = (mb & 1) * 256 + wr * 128 + mi * 16 + quad * 4;
                ushort4 pk;
                pk.x = f2bf(acc[mi][n][0]); pk.y = f2bf(acc[mi][n][1]);
                pk.z = f2bf(acc[mi][n][2]); pk.w = f2bf(acc[mi][n][3]);
                *(ushort4*)&Vt[(size_t)((b_idx * Hn + h) * Dn + d) * Sn + srow] = pk;
            }
    }
}

// ---------------------------------------------------------------- attention
// grid (2 qhalf, 512 bh), 256 thr (4 waves). S^T form (see round 6 notes).
// Round 12: K/V double-buffered, counted vmcnt(4) gate (chunk k+1's 4 loads
// stay in flight across chunk k's QK+softmax+PV compute). Mask row preloaded
// in prologue -> uniform per-wave vmcnt counts.
__global__ __launch_bounds__(256) void attn_kernel(const unsigned short* __restrict__ Q,
                                                   const unsigned short* __restrict__ K,
                                                   const unsigned short* __restrict__ Vt,
                                                   const float* __restrict__ mask,
                                                   unsigned short* __restrict__ attn) {
    int qhalf = blockIdx.x, bh = blockIdx.y;
    int h = bh & 7, b = bh >> 3;
    __shared__ __align__(16) unsigned short Kc[2][64 * 64];     // [buf][key][d] swz
    __shared__ __align__(16) unsigned short Vc[2][64 * 64];     // [buf][d][key] swz
    __shared__ __align__(16) unsigned short Ps[4][4 * 16 * 64]; // [wave][strip][q][key]
    __shared__ float maskv[512];                                // whole row, preloaded
    int tid = threadIdx.x;
    int w = tid >> 6, lane = tid & 63, quad = lane >> 4, l16 = lane & 15;
    int l7 = l16 & 7;

    const unsigned short* Qg = Q + (size_t)(bh * Sn + qhalf * 256) * Dn;
    const unsigned short* Kg = K + (size_t)(bh * Sn) * Dn;
    const unsigned short* Vg = Vt + (size_t)(bh * Dn) * Sn;

    // Q frags (A/B lane layouts identical), registers, whole kernel
    s8v aq[4][2];
#pragma unroll
    for (int i = 0; i < 4; i++)
#pragma unroll
        for (int ks = 0; ks < 2; ks++)
            aq[i][ks] = *(const s8v*)&Qg[((w * 4 + i) * 16 + l16) * 64 + ks * 32 + quad * 8];

    f4v acc[4][4];
    float psum[4] = {0.f, 0.f, 0.f, 0.f};
#pragma unroll
    for (int i = 0; i < 4; i++)
#pragma unroll
        for (int n = 0; n < 4; n++) acc[i][n] = (f4v){0.f, 0.f, 0.f, 0.f};

    // staging geometry: each async16 covers 8 rows; wave w rows w*16..w*16+15
    int srow0 = w * 16 + (lane >> 3);
    int srow1 = srow0 + 8;
    int gseg0 = ((lane & 7) ^ (srow0 & 7)) * 8;   // global seg so LDS[p] = g ^ (row&7)
    int gseg1 = ((lane & 7) ^ (srow1 & 7)) * 8;
    int kd0 = (w * 16) * 64, kd1 = (w * 16 + 8) * 64;

    unsigned short* Pw = Ps[w];
    int wbase = l16 * 64 + (quad & 1) * 4;        // P write: row l16 + sub-offset
    const float cM = -1.4426950409e10f;           // -1e10 * log2(e)

    // prologue: chunk 0 into buf 0 + whole mask row (uniform 6 loads/wave)
    async16(Kg + srow0 * 64 + gseg0, &Kc[0][kd0]);
    async16(Kg + srow1 * 64 + gseg1, &Kc[0][kd1]);
    async16(Vg + srow0 * 512 + gseg0, &Vc[0][kd0]);
    async16(Vg + srow1 * 512 + gseg1, &Vc[0][kd1]);
    async4(mask + b * Sn + w * 128 + lane, &maskv[w * 128]);
    async4(mask + b * Sn + w * 128 + 64 + lane, &maskv[w * 128 + 64]);
    asm volatile("s_waitcnt vmcnt(0)" ::: "memory");
    __builtin_amdgcn_s_barrier();

    for (int kc = 0; kc < 8; kc++) {
        int cur = kc & 1, nxt = cur ^ 1;
        if (kc < 7) {                              // stage chunk kc+1 into buf^1
            async16(Kg + ((kc + 1) * 64 + srow0) * 64 + gseg0, &Kc[nxt][kd0]);
            async16(Kg + ((kc + 1) * 64 + srow1) * 64 + gseg1, &Kc[nxt][kd1]);
            async16(Vg + srow0 * 512 + (kc + 1) * 64 + gseg0, &Vc[nxt][kd0]);
            async16(Vg + srow1 * 512 + (kc + 1) * 64 + gseg1, &Vc[nxt][kd1]);
            asm volatile("s_waitcnt vmcnt(4)" ::: "memory");   // chunk kc landed
        } else {
            asm volatile("s_waitcnt vmcnt(0)" ::: "memory");
        }
        __builtin_amdgcn_s_barrier();              // all waves' chunk kc ready

        // ---- S^T = K Q^T per key-tile n; bk shared across all 4 strips ----
#pragma unroll
        for (int n = 0; n < 4; n++) {
            s8v bk0 = *(const s8v*)&Kc[cur][(n * 16 + l16) * 64 + (quad ^ l7) * 8];
            s8v bk1 = *(const s8v*)&Kc[cur][(n * 16 + l16) * 64 + ((4 + quad) ^ l7) * 8];
            float4 mv = *(const float4*)&maskv[kc * 64 + n * 16 + quad * 4];
            float m0 = mv.x * cM, m1 = mv.y * cM, m2 = mv.z * cM, m3 = mv.w * cM;
            int wseg = ((n * 2 + (quad >> 1)) ^ l7) * 8;
            f4v sacc[4];
#pragma unroll
            for (int i = 0; i < 4; i++) {
                sacc[i] = __builtin_amdgcn_mfma_f32_16x16x32_bf16(
                              bk0, aq[i][0], (f4v){0.f, 0.f, 0.f, 0.f}, 0, 0, 0);
                sacc[i] = __builtin_amdgcn_mfma_f32_16x16x32_bf16(
                              bk1, aq[i][1], sacc[i], 0, 0, 0);
            }
#pragma unroll
            for (int i = 0; i < 4; i++) {
                unsigned int u0 = __float_as_uint(__builtin_amdgcn_exp2f(sacc[i][0] + m0));
                unsigned int u1 = __float_as_uint(__builtin_amdgcn_exp2f(sacc[i][1] + m1));
                unsigned int u2 = __float_as_uint(__builtin_amdgcn_exp2f(sacc[i][2] + m2));
                unsigned int u3 = __float_as_uint(__builtin_amdgcn_exp2f(sacc[i][3] + m3));
                psum[i] += __uint_as_float(u0 & 0xffff0000u) + __uint_as_float(u1 & 0xffff0000u)
                         + __uint_as_float(u2 & 0xffff0000u) + __uint_as_float(u3 & 0xffff0000u);
                uint2 pk;
                pk.x = (u0 >> 16) | (u1 & 0xffff0000u);
                pk.y = (u2 >> 16) | (u3 & 0xffff0000u);
                *(uint2*)&Pw[(i << 10) + wbase + wseg] = pk;
            }
        }
        // Ps is wave-private; DS ops in-order per wave -> no barrier needed.

        // ---- O += P V : ks-outer, ap/bv shared across strips ----
#pragma unroll
        for (int ks = 0; ks < 2; ks++) {
            int sw = ((ks * 4 + quad) ^ l7) * 8;
            s8v ap[4];
#pragma unroll
            for (int i = 0; i < 4; i++)
                ap[i] = *(const s8v*)&Pw[(i << 10) + l16 * 64 + sw];
#pragma unroll
            for (int n = 0; n < 4; n++) {
                s8v bv = *(const s8v*)&Vc[cur][(n * 16 + l16) * 64 + sw];
#pragma unroll
                for (int i = 0; i < 4; i++)
                    acc[i][n] = __builtin_amdgcn_mfma_f32_16x16x32_bf16(ap[i], bv, acc[i][n], 0, 0, 0);
            }
        }
        // reads of Kc/Vc[cur] complete before next iter overwrites buf^1
        asm volatile("s_waitcnt lgkmcnt(0)" ::: "memory");
        __builtin_amdgcn_s_barrier();
    }

    // deferred normalization: psum[i] is quad-partial for query l16
#pragma unroll
    for (int i = 0; i < 4; i++) {
        float s = psum[i];
        s += __shfl_xor(s, 16, 64);
        s += __shfl_xor(s, 32, 64);               // every lane: total for query l16
        float inv[4];
#pragma unroll
        for (int r = 0; r < 4; r++)
            inv[r] = 1.0f / __shfl(s, quad * 4 + r, 64);
#pragma unroll
        for (int n = 0; n < 4; n++)
#pragma unroll
            for (int r = 0; r < 4; r++) {
                int query = qhalf * 256 + (w * 4 + i) * 16 + quad * 4 + r;
                int col = h * 64 + n * 16 + l16;
                attn[(size_t)(b * Sn + query) * (Hn * Dn) + col] = f2bf(acc[i][n][r] * inv[r]);
            }
    }
}

// ---------------------------------------------------------------- outproj
// out[32768,512] = attn[32768,512] x WOt^T, fp32 out. grid (4 nb, 256 mb).
// Plain __syncthreads 2-phase dbuf (counted-2ph regressed on qkv — reverted).
// Swapped mfma(B,A): lane holds 4 consecutive cols -> float4 stores.
__global__ __launch_bounds__(256) void outproj(const unsigned short* __restrict__ attn,
                                               const unsigned short* __restrict__ WOt,
                                               float* __restrict__ out) {
    int nb = blockIdx.x, mb = blockIdx.y;
    __shared__ __align__(16) unsigned short At[2][128 * 64];
    __shared__ __align__(16) unsigned short Bt[2][128 * 64];
    int tid = threadIdx.x;
    int w = tid >> 6, lane = tid & 63, quad = lane >> 4, l16 = lane & 15;
    int wr = w >> 1, wc = w & 1;
    int lrow = lane >> 3;
    int lseg = ((lane & 7) ^ lrow) * 8;

    f4v acc[4][4];
#pragma unroll
    for (int i = 0; i < 4; i++)
#pragma unroll
        for (int n = 0; n < 4; n++) acc[i][n] = (f4v){0.f, 0.f, 0.f, 0.f};

    const unsigned short* Ag = attn + (size_t)mb * 128 * 512;
    const unsigned short* Bg = WOt + (size_t)nb * 128 * 512;

    // prologue: stage chunk 0
#pragma unroll
    for (int i = 0; i < 4; i++) {
        int r0 = w * 32 + i * 8;
        async16(Ag + (r0 + lrow) * 512 + lseg, &At[0][r0 * 64]);
        async16(Bg + (r0 + lrow) * 512 + lseg, &Bt[0][r0 * 64]);
    }
    __syncthreads();

    int cur = 0;
    for (int kc = 0; kc < 8; kc++) {
        if (kc < 7) {
            int nxt = cur ^ 1;
#pragma unroll
            for (int i = 0; i < 4; i++) {
                int r0 = w * 32 + i * 8;
                async16(Ag + (r0 + lrow) * 512 + (kc + 1) * 64 + lseg, &At[nxt][r0 * 64]);
                async16(Bg + (r0 + lrow) * 512 + (kc + 1) * 64 + lseg, &Bt[nxt][r0 * 64]);
            }
        }
#pragma unroll
        for (int ks = 0; ks < 2; ks++) {
            int sw = ((ks * 4 + quad) ^ (l16 & 7)) * 8;
            s8v a[4], b[4];
#pragma unroll
            for (int i = 0; i < 4; i++)
                a[i] = *(const s8v*)&At[cur][(wr * 64 + i * 16 + l16) * 64 + sw];
#pragma unroll
            for (int n = 0; n < 4; n++)
                b[n] = *(const s8v*)&Bt[cur][(wc * 64 + n * 16 + l16) * 64 + sw];
#pragma unroll
            for (int i = 0; i < 4; i++)
#pragma unroll
                for (int n = 0; n < 4; n++)
                    acc[i][n] = __builtin_amdgcn_mfma_f32_16x16x32_bf16(b[n], a[i], acc[i][n], 0, 0, 0);
        }
        if (kc < 7) __syncthreads();
        cur ^= 1;
    }
    // swapped: acc[i][n][r] -> row = mb*128+wr*64+i*16+l16, col = nb*128+wc*64+n*16+quad*4+r
#pragma unroll
    for (int i = 0; i < 4; i++)
#pragma unroll
        for (int n = 0; n < 4; n++) {
            int row = mb * 128 + wr * 64 + i * 16 + l16;
            int col = nb * 128 + wc * 64 + n * 16 + quad * 4;
            float4 o;
            o.x = acc[i][n][0]; o.y = acc[i][n][1];
            o.z = acc[i][n][2]; o.w = acc[i][n][3];
            *(float4*)&out[(size_t)row * 512 + col] = o;
        }
}

// ---------------------------------------------------------------- launch
extern "C" void kernel_launch(void* const* d_in, const int* in_sizes, int n_in,
                              void* d_out, int out_size, void* d_ws, size_t ws_size,
                              hipStream_t stream) {
    const float* x    = (const float*)d_in[0];
    const float* mask = (const float*)d_in[1];
    const float* WQ   = (const float*)d_in[2];
    const float* WK   = (const float*)d_in[3];
    const float* WV   = (const float*)d_in[4];
    const float* BE   = (const float*)d_in[5];
    const float* WO   = (const float*)d_in[6];
    float* out = (float*)d_out;

    char* ws = (char*)d_ws;
    unsigned short* hbf   = (unsigned short*)(ws);                 // 33554432 B
    unsigned short* Wqkvt = (unsigned short*)(ws + 33554432);      //  1572864 B
    unsigned short* WOt   = (unsigned short*)(ws + 35127296);      //   524288 B
    unsigned short* Qp    = (unsigned short*)(ws + 35651584);      // 33554432 B
    unsigned short* Kp    = (unsigned short*)(ws + 69206016);      // 33554432 B
    unsigned short* Vtp   = (unsigned short*)(ws + 102760448);     // 33554432 B
    unsigned short* attnp = (unsigned short*)(ws + 136314880);     // 33554432 B

    prep_h<<<16384, 256, 0, stream>>>(x, BE, hbf);
    prep_w<<<4096, 256, 0, stream>>>(WQ, WK, WV, WO, Wqkvt, WOt);
    qkv_gemm<<<dim3(6, 128), 512, 0, stream>>>(hbf, Wqkvt, Qp, Kp, Vtp);
    attn_kernel<<<dim3(2, 512), 256, 0, stream>>>(Qp, Kp, Vtp, mask, attnp);
    outproj<<<dim3(4, 256), 256, 0, stream>>>(attnp, WOt, out);
}

// Round 7
// 287.086 us; speedup vs baseline: 1.0270x; 1.0270x over previous
//
#include <hip/hip_runtime.h>
#include <hip/hip_bf16.h>

// SelfAttentionLayer: B=64 S=512 E=512 H=8 D=64
// Round 13:
//  - attn_kernel: FULL revert to verified sync version (round-0; counted-dbuf
//    was a 2-phase regime-gate regression + occupancy loss 3->2 blocks/CU).
//  - outproj: ported to the 8-phase 256^2 template (same staging/gates as
//    qkv round-4 best; all waves swapped-mfma; fp32 float4 epilogue).
//    grid (2 nbv, 128 mb), 512 thr, 128KB LDS.
//  - prep_h + prep_w fused into prep_all (one fewer launch gap).
//  - qkv_gemm unchanged (round-4 staging/gates, best measured 77.6us).

#define Bn 64
#define Sn 512
#define En 512
#define Hn 8
#define Dn 64

typedef __attribute__((ext_vector_type(8))) short s8v;   // 8 bf16 = 4 VGPRs
typedef __attribute__((ext_vector_type(4))) float f4v;   // 4 fp32 acc

__device__ __forceinline__ unsigned short f2bf(float f) {
    union { float f; unsigned int u; } v; v.f = f;
    unsigned int u = v.u;
    u += 0x7fffu + ((u >> 16) & 1u);   // round-to-nearest-even
    return (unsigned short)(u >> 16);
}

__device__ __forceinline__ void async16(const unsigned short* g, unsigned short* l) {
    __builtin_amdgcn_global_load_lds((const __attribute__((address_space(1))) void*)g,
                                     (__attribute__((address_space(3))) void*)l, 16, 0, 0);
}
__device__ __forceinline__ void async4(const float* g, float* l) {
    __builtin_amdgcn_global_load_lds((const __attribute__((address_space(1))) void*)g,
                                     (__attribute__((address_space(3))) void*)l, 4, 0, 0);
}

// ---------------------------------------------------------------- prep_all
// blocks [0,16384): h = x + BE -> bf16.  blocks [16384,20480): weight repack.
__global__ __launch_bounds__(256) void prep_all(const float* __restrict__ x,
                                                const float* __restrict__ BE,
                                                const float* __restrict__ WQ,
                                                const float* __restrict__ WK,
                                                const float* __restrict__ WV,
                                                const float* __restrict__ WO,
                                                unsigned short* __restrict__ hbf,
                                                unsigned short* __restrict__ Wqkvt,
                                                unsigned short* __restrict__ WOt) {
    int bid = blockIdx.x;
    if (bid < 16384) {
        int i = (bid * 256 + threadIdx.x) * 4;
        int se = i % (Sn * En);
        float4 a = *(const float4*)(x + i);
        float4 b = *(const float4*)(BE + se);
        ushort4 o;
        o.x = f2bf(a.x + b.x); o.y = f2bf(a.y + b.y);
        o.z = f2bf(a.z + b.z); o.w = f2bf(a.w + b.w);
        *(ushort4*)(hbf + i) = o;
    } else {
        int idx = (bid - 16384) * 256 + threadIdx.x;
        const int NW = 3 * Hn * Dn * En;                   // 786432
        if (idx < NW) {
            int e = idx & 511;
            int d = (idx >> 9) & 63;
            int h = (idx >> 15) & 7;
            int m = idx >> 18;
            const float* W = (m == 0) ? WQ : (m == 1) ? WK : WV;
            Wqkvt[idx] = f2bf(W[(h * En + e) * Dn + d]);   // [m][h][d][e]
        } else {
            int j = idx - NW;
            int n = j & 511;
            int e = j >> 9;
            WOt[j] = f2bf(WO[n * En + e]);                  // WO_t[e][hd]
        }
    }
}

// ---------------------------------------------------------------- mfma8
__device__ __forceinline__ void mfma8(const s8v& a0k0, const s8v& a0k1,
                                      const s8v& a1k0, const s8v& a1k1,
                                      f4v* acc0, f4v* acc1,
                                      const s8v (&bq)[4][2], bool sw) {
    if (sw) {
#pragma unroll
        for (int n = 0; n < 4; n++) {
            acc0[n] = __builtin_amdgcn_mfma_f32_16x16x32_bf16(bq[n][0], a0k0, acc0[n], 0, 0, 0);
            acc0[n] = __builtin_amdgcn_mfma_f32_16x16x32_bf16(bq[n][1], a0k1, acc0[n], 0, 0, 0);
            acc1[n] = __builtin_amdgcn_mfma_f32_16x16x32_bf16(bq[n][0], a1k0, acc1[n], 0, 0, 0);
            acc1[n] = __builtin_amdgcn_mfma_f32_16x16x32_bf16(bq[n][1], a1k1, acc1[n], 0, 0, 0);
        }
    } else {
#pragma unroll
        for (int n = 0; n < 4; n++) {
            acc0[n] = __builtin_amdgcn_mfma_f32_16x16x32_bf16(a0k0, bq[n][0], acc0[n], 0, 0, 0);
            acc0[n] = __builtin_amdgcn_mfma_f32_16x16x32_bf16(a0k1, bq[n][1], acc0[n], 0, 0, 0);
            acc1[n] = __builtin_amdgcn_mfma_f32_16x16x32_bf16(a1k0, bq[n][0], acc1[n], 0, 0, 0);
            acc1[n] = __builtin_amdgcn_mfma_f32_16x16x32_bf16(a1k1, bq[n][1], acc1[n], 0, 0, 0);
        }
    }
}

// ---------------------------------------------------------------- qkv_gemm
// C[32768,1536] = hbf[32768,512] x Wqkvt^T. 8-phase 256^2 schedule
// (round-4 staging/gates — best measured).
__global__ __launch_bounds__(512, 2) void qkv_gemm(const unsigned short* __restrict__ hbf,
                                                   const unsigned short* __restrict__ Wqkvt,
                                                   unsigned short* __restrict__ Qo,
                                                   unsigned short* __restrict__ Ko,
                                                   unsigned short* __restrict__ Vt) {
    __shared__ __align__(16) unsigned short As[2][16384];   // 64KB
    __shared__ __align__(16) unsigned short Bs[2][16384];   // 64KB

    int lin = blockIdx.y * 6 + blockIdx.x;                  // 768 blocks
    int swz = (lin & 7) * 96 + (lin >> 3);                  // bijective XCD swizzle
    int mb = swz / 6, nbv = swz - mb * 6;

    int tid = threadIdx.x;
    int w = tid >> 6, lane = tid & 63, quad = lane >> 4, l16 = lane & 15, l7 = l16 & 7;
    int wr = w >> 2, wcn = w & 3;

    const unsigned short* Ag = hbf + (size_t)mb * 256 * 512;
    const unsigned short* Bg = Wqkvt + (size_t)nbv * 256 * 512;

    int colbase = nbv * 256 + wcn * 64;
    bool swapQK = colbase < 1024;

    // staging address constants (pre-swizzled global source, linear LDS dst)
    int ha = (lane >> 3) & 1;                               // A hi/lo half
    int ca = w * 4 + (lane >> 4);                           // A m-part 0..31
    int aG0 = (ca + 128 * ha) * 512 + ((lane & 7) ^ (ca & 7)) * 8;
    int rb0 = w * 8 + (lane >> 3);                          // B row 0..63
    int bG0 = rb0 * 512 + ((lane & 7) ^ (rb0 & 7)) * 8;

    // ds_read constants
    int arow = 2 * l16 + wr;                                // A interleaved row term
    int aseg0 = (quad ^ l7) * 8;                            // ks=0 swizzled seg
    int aseg1 = ((4 + quad) ^ l7) * 8;                      // ks=1

    f4v acc[8][4];
#pragma unroll
    for (int i = 0; i < 8; i++)
#pragma unroll
        for (int n = 0; n < 4; n++) acc[i][n] = (f4v){0.f, 0.f, 0.f, 0.f};
    s8v bq[4][2];

#define STA8(o_, p_, kt_) async16(Ag + aG0 + (p_) * 16384 + (kt_) * 64, &As[o_][(p_) * 4096 + w * 512])
#define STB8(o_, q_, kt_) async16(Bg + bG0 + (q_) * 32768 + (kt_) * 64, &Bs[o_][(q_) * 4096 + w * 512])

#define PHASE8(P, STAGES, GATE)                                                   \
    do {                                                                          \
        if ((P) == 0) {                                                           \
            _Pragma("unroll")                                                     \
            for (int n = 0; n < 4; n++) {                                         \
                int br = (wcn * 64 + n * 16 + l16) * 64;                          \
                bq[n][0] = *(const s8v*)&Bs_s[br + aseg0];                        \
                bq[n][1] = *(const s8v*)&Bs_s[br + aseg1];                        \
            }                                                                     \
        }                                                                         \
        s8v a0k0 = *(const s8v*)&As_s[(((P) * 2 + 0) * 32 + arow) * 64 + aseg0];  \
        s8v a0k1 = *(const s8v*)&As_s[(((P) * 2 + 0) * 32 + arow) * 64 + aseg1];  \
        s8v a1k0 = *(const s8v*)&As_s[(((P) * 2 + 1) * 32 + arow) * 64 + aseg0];  \
        s8v a1k1 = *(const s8v*)&As_s[(((P) * 2 + 1) * 32 + arow) * 64 + aseg1];  \
        STAGES;                                                                   \
        __builtin_amdgcn_s_barrier();                                             \
        asm volatile("s_waitcnt lgkmcnt(0)" ::: "memory");                        \
        __builtin_amdgcn_s_setprio(1);                                            \
        mfma8(a0k0, a0k1, a1k0, a1k1, &acc[(P) * 2][0], &acc[(P) * 2 + 1][0], bq, swapQK); \
        __builtin_amdgcn_s_setprio(0);                                            \
        GATE;                                                                     \
        __builtin_amdgcn_s_barrier();                                             \
    } while (0)

    // prologue: K-tile 0 fully staged into slot 0, drained once
    STB8(0, 0, 0); STB8(0, 1, 0); STB8(0, 2, 0); STB8(0, 3, 0);
    STA8(0, 0, 0); STA8(0, 1, 0); STA8(0, 2, 0); STA8(0, 3, 0);
    asm volatile("s_waitcnt vmcnt(0)" ::: "memory");
    __builtin_amdgcn_s_barrier();

    for (int k = 0; k < 7; k++) {
        int s = k & 1, o = s ^ 1, kt = k + 1;
        const unsigned short* As_s = &As[s][0];
        const unsigned short* Bs_s = &Bs[s][0];
        PHASE8(0, { STB8(o, 0, kt); STB8(o, 1, kt); STA8(o, 0, kt); },
               asm volatile("s_waitcnt vmcnt(6)" ::: "memory"));
        PHASE8(1, { STB8(o, 2, kt); STA8(o, 1, kt); },
               asm volatile("s_waitcnt vmcnt(6)" ::: "memory"));
        PHASE8(2, { STB8(o, 3, kt); STA8(o, 2, kt); },
               asm volatile("s_waitcnt vmcnt(7)" ::: "memory"));
        PHASE8(3, { STA8(o, 3, kt); },
               asm volatile("s_waitcnt vmcnt(2)" ::: "memory"));
    }
    {   // tail K-tile 7 (slot 1): no staging, gradual drain
        const unsigned short* As_s = &As[1][0];
        const unsigned short* Bs_s = &Bs[1][0];
        PHASE8(0, {}, asm volatile("s_waitcnt vmcnt(3)" ::: "memory"));
        PHASE8(1, {}, asm volatile("s_waitcnt vmcnt(1)" ::: "memory"));
        PHASE8(2, {}, asm volatile("s_waitcnt vmcnt(0)" ::: "memory"));
        PHASE8(3, {}, (void)0);
    }
#undef PHASE8
#undef STA8
#undef STB8

    int mat = colbase >> 9;
    int h = (colbase >> 6) & 7;
    int b_idx = mb >> 1;
    const float qscale = 0.06375873f;   // log2(e)/sqrt(512): scale + exp->exp2 fold

    if (swapQK) {
        unsigned short* op = (mat == 0) ? Qo : Ko;
        float sc = (mat == 0) ? qscale : 1.0f;
#pragma unroll
        for (int mi = 0; mi < 8; mi++)
#pragma unroll
            for (int n = 0; n < 4; n++) {
                int s_ = (mb & 1) * 256 + wr * 128 + mi * 16 + l16;
                int d0 = n * 16 + quad * 4;
                ushort4 pk;
                pk.x = f2bf(acc[mi][n][0] * sc);
                pk.y = f2bf(acc[mi][n][1] * sc);
                pk.z = f2bf(acc[mi][n][2] * sc);
                pk.w = f2bf(acc[mi][n][3] * sc);
                *(ushort4*)&op[(size_t)((b_idx * Hn + h) * Sn + s_) * Dn + d0] = pk;
            }
    } else {
#pragma unroll
        for (int mi = 0; mi < 8; mi++)
#pragma unroll
            for (int n = 0; n < 4; n++) {
                int d = n * 16 + l16;
                int srow = (mb & 1) * 256 + wr * 128 + mi * 16 + quad * 4;
                ushort4 pk;
                pk.x = f2bf(acc[mi][n][0]); pk.y = f2bf(acc[mi][n][1]);
                pk.z = f2bf(acc[mi][n][2]); pk.w = f2bf(acc[mi][n][3]);
                *(ushort4*)&Vt[(size_t)((b_idx * Hn + h) * Dn + d) * Sn + srow] = pk;
            }
    }
}

// ---------------------------------------------------------------- attention
// grid (2 qhalf, 512 bh), 256 thr (4 waves). Verified sync version (round 0).
__global__ __launch_bounds__(256) void attn_kernel(const unsigned short* __restrict__ Q,
                                                   const unsigned short* __restrict__ K,
                                                   const unsigned short* __restrict__ Vt,
                                                   const float* __restrict__ mask,
                                                   unsigned short* __restrict__ attn) {
    int qhalf = blockIdx.x, bh = blockIdx.y;
    int h = bh & 7, b = bh >> 3;
    __shared__ __align__(16) unsigned short Kc[64 * 64];        // [key][d] swizzled
    __shared__ __align__(16) unsigned short Vc[64 * 64];        // [d][key] swizzled
    __shared__ __align__(16) unsigned short Ps[4][4 * 16 * 64]; // [wave][strip][q][key]
    __shared__ float maskv[64];
    int tid = threadIdx.x;
    int w = tid >> 6, lane = tid & 63, quad = lane >> 4, l16 = lane & 15;
    int l7 = l16 & 7;

    const unsigned short* Qg = Q + (size_t)(bh * Sn + qhalf * 256) * Dn;
    const unsigned short* Kg = K + (size_t)(bh * Sn) * Dn;
    const unsigned short* Vg = Vt + (size_t)(bh * Dn) * Sn;

    // Q frags (A/B lane layouts identical), registers, whole kernel
    s8v aq[4][2];
#pragma unroll
    for (int i = 0; i < 4; i++)
#pragma unroll
        for (int ks = 0; ks < 2; ks++)
            aq[i][ks] = *(const s8v*)&Qg[((w * 4 + i) * 16 + l16) * 64 + ks * 32 + quad * 8];

    f4v acc[4][4];
    float psum[4] = {0.f, 0.f, 0.f, 0.f};
#pragma unroll
    for (int i = 0; i < 4; i++)
#pragma unroll
        for (int n = 0; n < 4; n++) acc[i][n] = (f4v){0.f, 0.f, 0.f, 0.f};

    // staging: each async16 covers 8 rows (64 lanes x 16B); wave w rows w*16..+15
    int srow0 = w * 16 + (lane >> 3);
    int srow1 = srow0 + 8;
    int gseg0 = ((lane & 7) ^ (srow0 & 7)) * 8;   // global seg so LDS[p] = g ^ (row&7)
    int gseg1 = ((lane & 7) ^ (srow1 & 7)) * 8;
    unsigned short* kdst0 = &Kc[(w * 16) * 64];
    unsigned short* kdst1 = &Kc[(w * 16 + 8) * 64];
    unsigned short* vdst0 = &Vc[(w * 16) * 64];
    unsigned short* vdst1 = &Vc[(w * 16 + 8) * 64];

    unsigned short* Pw = Ps[w];
    int wbase = l16 * 64 + (quad & 1) * 4;        // P write: row l16 + sub-offset
    const float cM = -1.4426950409e10f;           // -1e10 * log2(e)

    for (int kc = 0; kc < 8; kc++) {
        __syncthreads();                          // all waves done with prev chunk
        async16(Kg + (kc * 64 + srow0) * 64 + gseg0, kdst0);
        async16(Kg + (kc * 64 + srow1) * 64 + gseg1, kdst1);
        async16(Vg + srow0 * 512 + kc * 64 + gseg0, vdst0);
        async16(Vg + srow1 * 512 + kc * 64 + gseg1, vdst1);
        if (w == 0) async4(mask + b * Sn + kc * 64 + lane, maskv);
        __syncthreads();                          // vmcnt drained -> chunk ready

        // ---- S^T = K Q^T per key-tile n; bk shared across all 4 strips ----
#pragma unroll
        for (int n = 0; n < 4; n++) {
            s8v bk0 = *(const s8v*)&Kc[(n * 16 + l16) * 64 + (quad ^ l7) * 8];
            s8v bk1 = *(const s8v*)&Kc[(n * 16 + l16) * 64 + ((4 + quad) ^ l7) * 8];
            float4 mv = *(const float4*)&maskv[n * 16 + quad * 4];
            float m0 = mv.x * cM, m1 = mv.y * cM, m2 = mv.z * cM, m3 = mv.w * cM;
            int wseg = ((n * 2 + (quad >> 1)) ^ l7) * 8;
            f4v sacc[4];
#pragma unroll
            for (int i = 0; i < 4; i++) {
                sacc[i] = __builtin_amdgcn_mfma_f32_16x16x32_bf16(
                              bk0, aq[i][0], (f4v){0.f, 0.f, 0.f, 0.f}, 0, 0, 0);
                sacc[i] = __builtin_amdgcn_mfma_f32_16x16x32_bf16(
                              bk1, aq[i][1], sacc[i], 0, 0, 0);
            }
#pragma unroll
            for (int i = 0; i < 4; i++) {
                unsigned int u0 = __float_as_uint(__builtin_amdgcn_exp2f(sacc[i][0] + m0));
                unsigned int u1 = __float_as_uint(__builtin_amdgcn_exp2f(sacc[i][1] + m1));
                unsigned int u2 = __float_as_uint(__builtin_amdgcn_exp2f(sacc[i][2] + m2));
                unsigned int u3 = __float_as_uint(__builtin_amdgcn_exp2f(sacc[i][3] + m3));
                psum[i] += __uint_as_float(u0 & 0xffff0000u) + __uint_as_float(u1 & 0xffff0000u)
                         + __uint_as_float(u2 & 0xffff0000u) + __uint_as_float(u3 & 0xffff0000u);
                uint2 pk;
                pk.x = (u0 >> 16) | (u1 & 0xffff0000u);
                pk.y = (u2 >> 16) | (u3 & 0xffff0000u);
                *(uint2*)&Pw[(i << 10) + wbase + wseg] = pk;
            }
        }
        // Ps is wave-private; DS ops in-order per wave -> no barrier needed.

        // ---- O += P V : ks-outer, ap/bv shared across strips ----
#pragma unroll
        for (int ks = 0; ks < 2; ks++) {
            int sw = ((ks * 4 + quad) ^ l7) * 8;
            s8v ap[4];
#pragma unroll
            for (int i = 0; i < 4; i++)
                ap[i] = *(const s8v*)&Pw[(i << 10) + l16 * 64 + sw];
#pragma unroll
            for (int n = 0; n < 4; n++) {
                s8v bv = *(const s8v*)&Vc[(n * 16 + l16) * 64 + sw];
#pragma unroll
                for (int i = 0; i < 4; i++)
                    acc[i][n] = __builtin_amdgcn_mfma_f32_16x16x32_bf16(ap[i], bv, acc[i][n], 0, 0, 0);
            }
        }
    }

    // deferred normalization: psum[i] is quad-partial for query l16
#pragma unroll
    for (int i = 0; i < 4; i++) {
        float s = psum[i];
        s += __shfl_xor(s, 16, 64);
        s += __shfl_xor(s, 32, 64);               // every lane: total for query l16
        float inv[4];
#pragma unroll
        for (int r = 0; r < 4; r++)
            inv[r] = 1.0f / __shfl(s, quad * 4 + r, 64);
#pragma unroll
        for (int n = 0; n < 4; n++)
#pragma unroll
            for (int r = 0; r < 4; r++) {
                int query = qhalf * 256 + (w * 4 + i) * 16 + quad * 4 + r;
                int col = h * 64 + n * 16 + l16;
                attn[(size_t)(b * Sn + query) * (Hn * Dn) + col] = f2bf(acc[i][n][r] * inv[r]);
            }
    }
}

// ---------------------------------------------------------------- outproj
// out[32768,512] = attn[32768,512] x WOt^T, fp32 out. 8-phase 256^2 template
// (same staging/gates as qkv). grid (2 nbv, 128 mb), 512 thr, 128KB LDS.
// All waves swapped mfma(B,A): lane holds 4 consecutive cols -> float4.
__global__ __launch_bounds__(512, 2) void outproj(const unsigned short* __restrict__ attn,
                                                  const unsigned short* __restrict__ WOt,
                                                  float* __restrict__ out) {
    __shared__ __align__(16) unsigned short As[2][16384];   // 64KB
    __shared__ __align__(16) unsigned short Bs[2][16384];   // 64KB

    int lin = blockIdx.y * 2 + blockIdx.x;                  // 256 blocks
    int swz = (lin & 7) * 32 + (lin >> 3);                  // bijective XCD swizzle
    int mb = swz >> 1, nbv = swz & 1;

    int tid = threadIdx.x;
    int w = tid >> 6, lane = tid & 63, quad = lane >> 4, l16 = lane & 15, l7 = l16 & 7;
    int wr = w >> 2, wcn = w & 3;

    const unsigned short* Ag = attn + (size_t)mb * 256 * 512;
    const unsigned short* Bg = WOt + (size_t)nbv * 256 * 512;

    // staging address constants (pre-swizzled global source, linear LDS dst)
    int ha = (lane >> 3) & 1;
    int ca = w * 4 + (lane >> 4);
    int aG0 = (ca + 128 * ha) * 512 + ((lane & 7) ^ (ca & 7)) * 8;
    int rb0 = w * 8 + (lane >> 3);
    int bG0 = rb0 * 512 + ((lane & 7) ^ (rb0 & 7)) * 8;

    // ds_read constants
    int arow = 2 * l16 + wr;
    int aseg0 = (quad ^ l7) * 8;
    int aseg1 = ((4 + quad) ^ l7) * 8;

    f4v acc[8][4];
#pragma unroll
    for (int i = 0; i < 8; i++)
#pragma unroll
        for (int n = 0; n < 4; n++) acc[i][n] = (f4v){0.f, 0.f, 0.f, 0.f};
    s8v bq[4][2];

#define STA8(o_, p_, kt_) async16(Ag + aG0 + (p_) * 16384 + (kt_) * 64, &As[o_][(p_) * 4096 + w * 512])
#define STB8(o_, q_, kt_) async16(Bg + bG0 + (q_) * 32768 + (kt_) * 64, &Bs[o_][(q_) * 4096 + w * 512])

#define PHASE8(P, STAGES, GATE)                                                   \
    do {                                                                          \
        if ((P) == 0) {                                                           \
            _Pragma("unroll")                                                     \
            for (int n = 0; n < 4; n++) {                                         \
                int br = (wcn * 64 + n * 16 + l16) * 64;                          \
                bq[n][0] = *(const s8v*)&Bs_s[br + aseg0];                        \
                bq[n][1] = *(const s8v*)&Bs_s[br + aseg1];                        \
            }                                                                     \
        }                                                                         \
        s8v a0k0 = *(const s8v*)&As_s[(((P) * 2 + 0) * 32 + arow) * 64 + aseg0];  \
        s8v a0k1 = *(const s8v*)&As_s[(((P) * 2 + 0) * 32 + arow) * 64 + aseg1];  \
        s8v a1k0 = *(const s8v*)&As_s[(((P) * 2 + 1) * 32 + arow) * 64 + aseg0];  \
        s8v a1k1 = *(const s8v*)&As_s[(((P) * 2 + 1) * 32 + arow) * 64 + aseg1];  \
        STAGES;                                                                   \
        __builtin_amdgcn_s_barrier();                                             \
        asm volatile("s_waitcnt lgkmcnt(0)" ::: "memory");                        \
        __builtin_amdgcn_s_setprio(1);                                            \
        mfma8(a0k0, a0k1, a1k0, a1k1, &acc[(P) * 2][0], &acc[(P) * 2 + 1][0], bq, true); \
        __builtin_amdgcn_s_setprio(0);                                            \
        GATE;                                                                     \
        __builtin_amdgcn_s_barrier();                                             \
    } while (0)

    // prologue: K-tile 0 fully staged into slot 0, drained once
    STB8(0, 0, 0); STB8(0, 1, 0); STB8(0, 2, 0); STB8(0, 3, 0);
    STA8(0, 0, 0); STA8(0, 1, 0); STA8(0, 2, 0); STA8(0, 3, 0);
    asm volatile("s_waitcnt vmcnt(0)" ::: "memory");
    __builtin_amdgcn_s_barrier();

    for (int k = 0; k < 7; k++) {
        int s = k & 1, o = s ^ 1, kt = k + 1;
        const unsigned short* As_s = &As[s][0];
        const unsigned short* Bs_s = &Bs[s][0];
        PHASE8(0, { STB8(o, 0, kt); STB8(o, 1, kt); STA8(o, 0, kt); },
               asm volatile("s_waitcnt vmcnt(6)" ::: "memory"));
        PHASE8(1, { STB8(o, 2, kt); STA8(o, 1, kt); },
               asm volatile("s_waitcnt vmcnt(6)" ::: "memory"));
        PHASE8(2, { STB8(o, 3, kt); STA8(o, 2, kt); },
               asm volatile("s_waitcnt vmcnt(7)" ::: "memory"));
        PHASE8(3, { STA8(o, 3, kt); },
               asm volatile("s_waitcnt vmcnt(2)" ::: "memory"));
    }
    {   // tail
        const unsigned short* As_s = &As[1][0];
        const unsigned short* Bs_s = &Bs[1][0];
        PHASE8(0, {}, asm volatile("s_waitcnt vmcnt(3)" ::: "memory"));
        PHASE8(1, {}, asm volatile("s_waitcnt vmcnt(1)" ::: "memory"));
        PHASE8(2, {}, asm volatile("s_waitcnt vmcnt(0)" ::: "memory"));
        PHASE8(3, {}, (void)0);
    }
#undef PHASE8
#undef STA8
#undef STB8

    // swapped epilogue: row = mb*256+wr*128+mi*16+l16, col = nbv*256+wcn*64+n*16+quad*4
#pragma unroll
    for (int mi = 0; mi < 8; mi++)
#pragma unroll
        for (int n = 0; n < 4; n++) {
            int row = mb * 256 + wr * 128 + mi * 16 + l16;
            int col = nbv * 256 + wcn * 64 + n * 16 + quad * 4;
            float4 o;
            o.x = acc[mi][n][0]; o.y = acc[mi][n][1];
            o.z = acc[mi][n][2]; o.w = acc[mi][n][3];
            *(float4*)&out[(size_t)row * 512 + col] = o;
        }
}

// ---------------------------------------------------------------- launch
extern "C" void kernel_launch(void* const* d_in, const int* in_sizes, int n_in,
                              void* d_out, int out_size, void* d_ws, size_t ws_size,
                              hipStream_t stream) {
    const float* x    = (const float*)d_in[0];
    const float* mask = (const float*)d_in[1];
    const float* WQ   = (const float*)d_in[2];
    const float* WK   = (const float*)d_in[3];
    const float* WV   = (const float*)d_in[4];
    const float* BE   = (const float*)d_in[5];
    const float* WO   = (const float*)d_in[6];
    float* out = (float*)d_out;

    char* ws = (char*)d_ws;
    unsigned short* hbf   = (unsigned short*)(ws);                 // 33554432 B
    unsigned short* Wqkvt = (unsigned short*)(ws + 33554432);      //  1572864 B
    unsigned short* WOt   = (unsigned short*)(ws + 35127296);      //   524288 B
    unsigned short* Qp    = (unsigned short*)(ws + 35651584);      // 33554432 B
    unsigned short* Kp    = (unsigned short*)(ws + 69206016);      // 33554432 B
    unsigned short* Vtp   = (unsigned short*)(ws + 102760448);     // 33554432 B
    unsigned short* attnp = (unsigned short*)(ws + 136314880);     // 33554432 B

    prep_all<<<20480, 256, 0, stream>>>(x, BE, WQ, WK, WV, WO, hbf, Wqkvt, WOt);
    qkv_gemm<<<dim3(6, 128), 512, 0, stream>>>(hbf, Wqkvt, Qp, Kp, Vtp);
    attn_kernel<<<dim3(2, 512), 256, 0, stream>>>(Qp, Kp, Vtp, mask, attnp);
    outproj<<<dim3(2, 128), 512, 0, stream>>>(attnp, WOt, out);
}